// Round 14
// baseline (138.534 us; speedup 1.0000x reference)
//
#include <hip/hip_runtime.h>

typedef unsigned short ushort_t;
typedef __bf16 bf16x8 __attribute__((ext_vector_type(8)));
typedef float f32x4 __attribute__((ext_vector_type(4)));
typedef float f32x16 __attribute__((ext_vector_type(16)));

#define DEVI __device__ __forceinline__

constexpr int BSZ = 4;     // batch
constexpr int MDIM = 190;  // axial dim
constexpr int TDIM = 512;  // seq
constexpr int CDIM = 64;   // channels

DEVI ushort_t f2bf(float f) {
    union { float f; unsigned int u; } v; v.f = f;
    unsigned int u = v.u;
    u += 0x7FFFu + ((u >> 16) & 1u);   // round-to-nearest-even
    return (ushort_t)(u >> 16);
}

DEVI void gload16(ushort_t* ldsBase, const ushort_t* g) {
    __builtin_amdgcn_global_load_lds(
        (const __attribute__((address_space(1))) unsigned int*)g,
        (__attribute__((address_space(3))) unsigned int*)ldsBase, 16, 0, 0);
}

// ---------------------------------------------------------------- K1: fused v-projection + xsum partials
// vf[b][mblk48][n][ks32][cg2][lane64][elem8]
__global__ __launch_bounds__(256, 4) void k_vproj(const float* __restrict__ x,
                                                  const float* __restrict__ Wv,
                                                  const float* __restrict__ bv,
                                                  ushort_t* __restrict__ vf,
                                                  float* __restrict__ xsp) {
    __shared__ __align__(16) ushort_t xbf[64 * 72];
    __shared__ __align__(16) ushort_t WvT[64 * 72];
    __shared__ __align__(16) ushort_t vst[64 * 72];

    int tid = threadIdx.x;
    int bid = blockIdx.x;            // 512 = 4b * 8tt * 16mg
    int mg = bid & 15;
    int tt = (bid >> 4) & 7;
    int b = bid >> 7;
    int t0 = tt * 64;
    int mbase = mg * 12;
    int cnt = (mbase + 12 <= MDIM) ? 12 : (MDIM - mbase);   // 12 or 10

    int w = tid >> 6, lane = tid & 63;
    int la = lane & 15, lb = lane >> 4;
    int r = tid >> 2, seg = tid & 3;

    int chunk = tid >> 3, u = tid & 7;
    int ksr = chunk >> 3;
    int nn2 = (chunk >> 1) & 3;
    int lhi2 = chunk & 1;
    int d0 = u * 2;

#pragma unroll
    for (int rep = 0; rep < 16; ++rep) {
        int j = rep * 256 + tid;
        int ci = j >> 6, co = j & 63;
        WvT[co * 72 + ci] = f2bf(Wv[j]);
    }
    float bvv[4];
#pragma unroll
    for (int cf = 0; cf < 4; ++cf) bvv[cf] = bv[16 * cf + la];

    float xacc[16];
#pragma unroll
    for (int u2 = 0; u2 < 16; ++u2) xacc[u2] = 0.f;

    const size_t mstride = (size_t)TDIM * CDIM;  // 32768
    size_t xaddr = ((size_t)(b * MDIM + mbase) * TDIM + t0 + r) * CDIM + seg * 16;

    float4 xv[4];
#pragma unroll
    for (int u2 = 0; u2 < 4; ++u2) xv[u2] = *(const float4*)(x + xaddr + u2 * 4);

    f32x4 zz = {0.f, 0.f, 0.f, 0.f};

    for (int i = 0; i < cnt; ++i) {
#pragma unroll
        for (int u2 = 0; u2 < 4; ++u2) {
            xacc[u2 * 4 + 0] += xv[u2].x;
            xacc[u2 * 4 + 1] += xv[u2].y;
            xacc[u2 * 4 + 2] += xv[u2].z;
            xacc[u2 * 4 + 3] += xv[u2].w;
            ushort4 h;
            h.x = f2bf(xv[u2].x); h.y = f2bf(xv[u2].y);
            h.z = f2bf(xv[u2].z); h.w = f2bf(xv[u2].w);
            *(ushort4*)&xbf[r * 72 + seg * 16 + u2 * 4] = h;
        }
        __syncthreads();

        int inext = (i + 1 < cnt) ? (i + 1) : i;
        size_t xaddr2 = xaddr + (size_t)(inext - i) * mstride;
        float4 xv2[4];
#pragma unroll
        for (int u2 = 0; u2 < 4; ++u2) xv2[u2] = *(const float4*)(x + xaddr2 + u2 * 4);

        f32x4 acc2[4];
#pragma unroll
        for (int cf = 0; cf < 4; ++cf) acc2[cf] = zz;
#pragma unroll
        for (int ks = 0; ks < 2; ++ks) {
            bf16x8 aa = *(const bf16x8*)&xbf[(w * 16 + la) * 72 + ks * 32 + lb * 8];
#pragma unroll
            for (int cf = 0; cf < 4; ++cf) {
                bf16x8 bb = *(const bf16x8*)&WvT[(16 * cf + la) * 72 + ks * 32 + lb * 8];
                acc2[cf] = __builtin_amdgcn_mfma_f32_16x16x32_bf16(aa, bb, acc2[cf], 0, 0, 0);
            }
        }
#pragma unroll
        for (int cf = 0; cf < 4; ++cf) {
            ushort4 h;
            h.x = f2bf(acc2[cf][0] + bvv[cf]);
            h.y = f2bf(acc2[cf][1] + bvv[cf]);
            h.z = f2bf(acc2[cf][2] + bvv[cf]);
            h.w = f2bf(acc2[cf][3] + bvv[cf]);
            *(ushort4*)&vst[(16 * cf + la) * 72 + w * 16 + lb * 4] = h;   // vst[c][t_rel]
        }
        __syncthreads();

        int m = mbase + i;
        int mblk = m >> 2, mrel = m & 3;
        int cg = mrel >> 1, half = mrel & 1;
        size_t vfbase = ((((size_t)(b * 48 + mblk) * 4 + nn2) * 32 + (tt * 4 + ksr)) * 2 + cg) * 512
                      + (size_t)(lhi2 * 32 + half * 16 + d0) * 8;
        uint4 v0 = *(const uint4*)&vst[(nn2 * 16 + d0) * 72 + ksr * 16 + lhi2 * 8];
        uint4 v1 = *(const uint4*)&vst[(nn2 * 16 + d0 + 1) * 72 + ksr * 16 + lhi2 * 8];
        *(uint4*)(vf + vfbase) = v0;
        *(uint4*)(vf + vfbase + 8) = v1;

#pragma unroll
        for (int u2 = 0; u2 < 4; ++u2) xv[u2] = xv2[u2];
        xaddr = xaddr2;
    }

    if (mg == 15) {
        uint4 z4 = {0u, 0u, 0u, 0u};
#pragma unroll
        for (int pm = 190; pm < 192; ++pm) {
            int mblk = pm >> 2, mrel = pm & 3;
            int cg = mrel >> 1, half = mrel & 1;
            size_t vfbase = ((((size_t)(b * 48 + mblk) * 4 + nn2) * 32 + (tt * 4 + ksr)) * 2 + cg) * 512
                          + (size_t)(lhi2 * 32 + half * 16 + d0) * 8;
            *(uint4*)(vf + vfbase) = z4;
            *(uint4*)(vf + vfbase + 8) = z4;
        }
    }

    size_t sbase = ((size_t)(mg * 4 + b) * TDIM + t0 + r) * CDIM + seg * 16;
#pragma unroll
    for (int u2 = 0; u2 < 4; ++u2) {
        float4 o;
        o.x = xacc[u2 * 4 + 0]; o.y = xacc[u2 * 4 + 1];
        o.z = xacc[u2 * 4 + 2]; o.w = xacc[u2 * 4 + 3];
        *(float4*)(xsp + sbase + u2 * 4) = o;
    }
}

// ---------------------------------------------------------------- K1b: reduce 16 partials -> xsum; block 0 builds wpf
__global__ __launch_bounds__(256) void k_xsum2(const float* __restrict__ xsp,
                                               const float* __restrict__ Wp,
                                               float* __restrict__ xsum,
                                               ushort_t* __restrict__ wpf) {
    int tid = threadIdx.x;
    int idx = blockIdx.x * 256 + tid;   // 131072
    float s = 0.f;
#pragma unroll
    for (int p = 0; p < 16; ++p) s += xsp[(size_t)p * 131072 + idx];
    xsum[idx] = s;

    if (blockIdx.x == 0) {
#pragma unroll
        for (int rp = 0; rp < 16; ++rp) {
            int u = rp * 256 + tid;            // 0..4095
            int cf = u >> 11, kk = (u >> 9) & 3, lf = (u >> 3) & 63, j = u & 7;
            wpf[u] = f2bf(Wp[(kk * 16 + (lf >> 5) * 8 + j) * 64 + cf * 32 + (lf & 31)]);
        }
    }
}

// ---------------------------------------------------------------- K2: weights (qt/kt + softmax), frag-order output
__global__ __launch_bounds__(256) void k_weights(const float* __restrict__ xsum,
                                                 const float* __restrict__ Wq,
                                                 const float* __restrict__ bq,
                                                 const float* __restrict__ Wk,
                                                 const float* __restrict__ bk,
                                                 ushort_t* __restrict__ wf,
                                                 float* __restrict__ a_out) {
    __shared__ __align__(16) float kt[512][20];
    __shared__ __align__(16) float qt[32][20];
    __shared__ __align__(16) float xs[64][68];
    __shared__ __align__(16) float wcol[64][16];
    __shared__ float kbias[16], qbias[16];
    __shared__ __align__(16) ushort_t rowbuf[32][520];

    int tid = threadIdx.x;
    int bid = blockIdx.x;        // 256 blocks
    int tcn = bid & 15;          // t-chunk (32 rows) == tq
    int n = (bid >> 4) & 3;
    int b = bid >> 6;
    int t0 = tcn * 32;

    for (int j = tid; j < 1024; j += 256) {
        int c = j >> 4, d = j & 15;
        wcol[c][d] = Wk[c * 64 + n * 16 + d];
    }
    if (tid < 16) kbias[tid] = 190.0f * bk[n * 16 + tid];
    if (tid >= 16 && tid < 32) qbias[tid - 16] = 190.0f * bq[n * 16 + tid - 16];
    __syncthreads();

    for (int ch = 0; ch < 8; ++ch) {
        for (int j = tid; j < 4096; j += 256) {
            int t = j >> 6, c = j & 63;
            xs[t][c] = xsum[((size_t)(b * 512) + (ch * 64 + t)) * 64 + c];
        }
        __syncthreads();
#pragma unroll
        for (int o = 0; o < 4; ++o) {
            int oi = o * 256 + tid;
            int t = oi >> 4, d = oi & 15;
            float s = 0.f;
#pragma unroll
            for (int c = 0; c < 64; ++c) s += xs[t][c] * wcol[c][d];
            kt[ch * 64 + t][d] = s + kbias[d];
        }
        __syncthreads();
    }

    for (int j = tid; j < 1024; j += 256) {
        int c = j >> 4, d = j & 15;
        wcol[c][d] = Wq[c * 64 + n * 16 + d];
    }
    for (int j = tid; j < 2048; j += 256) {
        int t = j >> 6, c = j & 63;
        xs[t][c] = xsum[((size_t)(b * 512) + (t0 + t)) * 64 + c];
    }
    __syncthreads();
#pragma unroll
    for (int o = 0; o < 2; ++o) {
        int oi = o * 256 + tid;
        int t = oi >> 4, d = oi & 15;
        float s = 0.f;
#pragma unroll
        for (int c = 0; c < 64; ++c) s += xs[t][c] * wcol[c][d];
        qt[t][d] = s + qbias[d];
    }
    __syncthreads();

    const float scale = 0.01813692f;  // 1/sqrt(16*190)
    int w = tid >> 6, lane = tid & 63;
    for (int rr = 0; rr < 8; ++rr) {
        int r = w * 8 + rr;
        float qreg[16];
#pragma unroll
        for (int d = 0; d < 16; ++d) qreg[d] = qt[r][d];
        float lv[8];
#pragma unroll
        for (int i = 0; i < 8; ++i) {
            int k = lane + 64 * i;
            const float* kr = &kt[k][0];
            float s = 0.f;
#pragma unroll
            for (int d = 0; d < 16; ++d) s += qreg[d] * kr[d];
            lv[i] = s * scale;
        }
        float mx = lv[0];
#pragma unroll
        for (int i = 1; i < 8; ++i) mx = fmaxf(mx, lv[i]);
#pragma unroll
        for (int off = 32; off >= 1; off >>= 1) mx = fmaxf(mx, __shfl_xor(mx, off));
        float se = 0.f;
#pragma unroll
        for (int i = 0; i < 8; ++i) { lv[i] = __expf(lv[i] - mx); se += lv[i]; }
#pragma unroll
        for (int off = 32; off >= 1; off >>= 1) se += __shfl_xor(se, off);
        float inv = 1.0f / se;

        size_t abase = ((size_t)(n * 512 + (t0 + r))) * 512;
#pragma unroll
        for (int i = 0; i < 8; ++i) {
            float wv = lv[i] * inv;
            rowbuf[r][lane + 64 * i] = f2bf(wv);
            if (b == 0) a_out[abase + lane + 64 * i] = wv;
        }
    }
    __syncthreads();

    size_t wfbase = ((size_t)((b * 4 + n) * 16 + tcn)) * 32 * 512;
#pragma unroll
    for (int p = 0; p < 8; ++p) {
        int id = p * 256 + tid;          // 0..2047
        int ks = id >> 6;
        int lf = id & 63;
        int l31 = lf & 31, lhi = lf >> 5;
        uint4 v = *(const uint4*)&rowbuf[l31][ks * 16 + lhi * 8];
        *(uint4*)(wf + wfbase + (size_t)ks * 512 + lf * 8) = v;
    }
}

// ---------------------------------------------------------------- K4: LDS-shared blocked GEMM att.
// Block = (b, tt of 128t, mq of 8m). 1024 thr = 16 waves = (n, tq of 32t).
// Per K-step (BK=16 = one frag ks-unit): stage 32 chunks of 1KB (A: 16 = [n][tq], B: 16 = [mblk][n][cg])
// via global_load_lds, double-buffered 2x32KB, one barrier per step (m97 structure).
// All LDS reads are chunk_base + lane*16 -> conflict-free by construction.
// Epilogue: acc -> frag-order attS (64 chunks), fused GEMM2 with wpf, two 4m passes.
__global__ __launch_bounds__(1024, 4) void k_att(const ushort_t* __restrict__ wf,
                                                 const ushort_t* __restrict__ vf,
                                                 const ushort_t* __restrict__ wpf,
                                                 const float* __restrict__ bp,
                                                 float* __restrict__ out) {
    __shared__ __align__(16) ushort_t lds[32768];   // 64 KB: buf0 @0, buf1 @16384; epilogue attS reuses all

    int tid = threadIdx.x;
    int bid0 = blockIdx.x;                     // 384 = 4b * 24mq * 4tt
    int bid = (bid0 & 7) * 48 + (bid0 >> 3);   // XCD x -> logical [48x, 48x+48)
    // logical: bid = b*96 + mq*4 + tt  (tt fastest: B(mq) reused across tt within XCD; W_b (2MB) L2-resident)
    int tt = bid & 3;
    int mq = (bid >> 2) % 24;                  // 8 m each
    int b = bid / 96;

    int wid = tid >> 6, lane = tid & 63;
    int l31 = lane & 31, lhi = lane >> 5;
    int n = wid >> 2;        // head
    int tq = wid & 3;        // 32t quarter

    // ---- staging assignment: wave stages chunks 2w, 2w+1
    unsigned src0, src1;
    int sstr;
    {
        int c0 = 2 * wid, c1 = 2 * wid + 1;
        if (wid < 8) {   // A chunks: id = n*4 + tq
            int n0 = c0 >> 2, q0 = c0 & 3;
            int n1 = c1 >> 2, q1 = c1 & 3;
            src0 = (unsigned)((((b * 4 + n0) * 16 + tt * 4 + q0) * 32) * 512 + lane * 8);
            src1 = (unsigned)((((b * 4 + n1) * 16 + tt * 4 + q1) * 32) * 512 + lane * 8);
            sstr = 512;
        } else {         // B chunks: id-16 = (mblk*4+n)*2 + cg
            int e0 = c0 - 16, e1 = c1 - 16;
            int mb0 = e0 >> 3, n0 = (e0 >> 1) & 3, cg0 = e0 & 1;
            int mb1 = e1 >> 3, n1 = (e1 >> 1) & 3, cg1 = e1 & 1;
            src0 = (unsigned)((((((b * 48 + mq * 2 + mb0) * 4 + n0) * 32) * 2) + cg0) * 512 + lane * 8);
            src1 = (unsigned)((((((b * 48 + mq * 2 + mb1) * 4 + n1) * 32) * 2) + cg1) * 512 + lane * 8);
            sstr = 1024;
        }
    }
    ushort_t* dst0 = lds + (2 * wid) * 512 + lane * 8;
    ushort_t* dst1 = lds + (2 * wid + 1) * 512 + lane * 8;

    const ushort_t* srcbase0 = (wid < 8) ? wf : vf;

    f32x16 acc[4];
#pragma unroll
    for (int j = 0; j < 4; ++j) acc[j] = (f32x16)(0.f);

    int aoff = (n * 4 + tq) * 512 + lane * 8;      // wave's A chunk
    int boff[4];
#pragma unroll
    for (int j = 0; j < 4; ++j) {
        int mblk = j >> 1, cg = j & 1;
        boff[j] = (16 + (mblk * 4 + n) * 2 + cg) * 512 + lane * 8;
    }

    // ---- main loop: 32 K-steps, double-buffered, one barrier per step
    gload16(dst0, srcbase0 + src0);
    gload16(dst1, srcbase0 + src1);
    __syncthreads();

    for (int ks = 0; ks < 32; ++ks) {
        int par = ks & 1;
        if (ks < 31) {
            ushort_t* d0 = dst0 + (par ^ 1) * 16384;
            ushort_t* d1 = dst1 + (par ^ 1) * 16384;
            gload16(d0, srcbase0 + src0 + (unsigned)(ks + 1) * sstr);
            gload16(d1, srcbase0 + src1 + (unsigned)(ks + 1) * sstr);
        }
        const ushort_t* buf = lds + par * 16384;
        bf16x8 aa = *(const bf16x8*)(buf + aoff);
#pragma unroll
        for (int j = 0; j < 4; ++j) {
            bf16x8 bb = *(const bf16x8*)(buf + boff[j]);
            acc[j] = __builtin_amdgcn_mfma_f32_32x32x16_bf16(aa, bb, acc[j], 0, 0, 0);
        }
        __syncthreads();
    }

    // ---- epilogue: two 4m passes. attS frag-order: chunk = (mloc*4 + tq')*4 + kk(=n), 64 chunks = 64KB.
    float bpv[2];
#pragma unroll
    for (int cf = 0; cf < 2; ++cf) bpv[cf] = bp[cf * 32 + l31];

    int mloc2 = wid >> 2;        // GEMM2 wave mapping: (mloc, tq2) -- 16 waves? mloc2 in 0..3
    int tq2 = wid & 3;

#pragma unroll
    for (int h = 0; h < 2; ++h) {
        if (h) __syncthreads();   // pass-0 GEMM2 reads done before overwrite
        // write acc[2h], acc[2h+1] into attS
#pragma unroll
        for (int jj = 0; jj < 2; ++jj) {
            int j = 2 * h + jj;
            f32x16 a = acc[j];
            int mloc = jj * 2 + (l31 >> 4);     // 0..3 within pass
            int d = l31 & 15;
            int chunkb = ((mloc * 4 + tq) * 4 + n) * 512;
#pragma unroll
            for (int r = 0; r < 16; ++r) {
                int t31 = (r & 3) + 8 * (r >> 2) + 4 * lhi;
                lds[chunkb + ((d >> 3) * 32 + t31) * 8 + (d & 7)] = f2bf(a[r]);
            }
        }
        __syncthreads();

        // GEMM2: wave (mloc2, tq2): C2[32t x 64c], K=64 (kk=n)
        f32x16 acc2[2];
#pragma unroll
        for (int cf = 0; cf < 2; ++cf) acc2[cf] = (f32x16)(0.f);
#pragma unroll
        for (int kk = 0; kk < 4; ++kk) {
            bf16x8 aa2 = *(const bf16x8*)(lds + ((mloc2 * 4 + tq2) * 4 + kk) * 512 + lane * 8);
#pragma unroll
            for (int cf = 0; cf < 2; ++cf) {
                bf16x8 bbf = *(const bf16x8*)(wpf + (cf * 4 + kk) * 512 + lane * 8);
                acc2[cf] = __builtin_amdgcn_mfma_f32_32x32x16_bf16(aa2, bbf, acc2[cf], 0, 0, 0);
            }
        }
        int m = mq * 8 + h * 4 + mloc2;
        if (m < 190) {
            size_t obase = ((size_t)(b * 190 + m) * 512 + tt * 128 + tq2 * 32) * 64;
#pragma unroll
            for (int cf = 0; cf < 2; ++cf)
#pragma unroll
                for (int r = 0; r < 16; ++r) {
                    int t31 = (r & 3) + 8 * (r >> 2) + 4 * lhi;
                    out[obase + (size_t)t31 * 64 + cf * 32 + l31] = acc2[cf][r] + bpv[cf];
                }
        }
    }
}

// ----------------------------------------------------------------
extern "C" void kernel_launch(void* const* d_in, const int* in_sizes, int n_in,
                              void* d_out, int out_size, void* d_ws, size_t ws_size,
                              hipStream_t stream) {
    const float* x  = (const float*)d_in[0];
    const float* Wq = (const float*)d_in[1];
    const float* bq = (const float*)d_in[2];
    const float* Wk = (const float*)d_in[3];
    const float* bk = (const float*)d_in[4];
    const float* Wv = (const float*)d_in[5];
    const float* bv = (const float*)d_in[6];
    const float* Wp = (const float*)d_in[7];
    const float* bp = (const float*)d_in[8];

    float* out = (float*)d_out;
    float* a_out = out + (size_t)BSZ * MDIM * TDIM * CDIM;   // 24903680

    // xsum partials in the out region (8 MB), fully overwritten by k_att later.
    float* xsp = out;

    float* xsum = (float*)d_ws;                                         // 512 KB
    ushort_t* wf = (ushort_t*)((char*)d_ws + 524288);                   // 8.39 MB
    ushort_t* vf = (ushort_t*)((char*)d_ws + 524288 + 8388608);         // 50.33 MB
    ushort_t* wpf = (ushort_t*)((char*)d_ws + 524288 + 8388608 + 50331648);  // 8 KB

    k_vproj<<<512, 256, 0, stream>>>(x, Wv, bv, vf, xsp);
    k_xsum2<<<512, 256, 0, stream>>>(xsp, Wp, xsum, wpf);
    k_weights<<<256, 256, 0, stream>>>(xsum, Wq, bq, Wk, bk, wf, a_out);
    k_att<<<384, 1024, 0, stream>>>(wf, vf, wpf, bp, out);
}

// Round 15
// 135.911 us; speedup vs baseline: 1.0193x; 1.0193x over previous
//
#include <hip/hip_runtime.h>

typedef unsigned short ushort_t;
typedef __bf16 bf16x8 __attribute__((ext_vector_type(8)));
typedef float f32x4 __attribute__((ext_vector_type(4)));
typedef float f32x16 __attribute__((ext_vector_type(16)));

#define DEVI __device__ __forceinline__

constexpr int BSZ = 4;     // batch
constexpr int MDIM = 190;  // axial dim
constexpr int TDIM = 512;  // seq
constexpr int CDIM = 64;   // channels

DEVI ushort_t f2bf(float f) {
    union { float f; unsigned int u; } v; v.f = f;
    unsigned int u = v.u;
    u += 0x7FFFu + ((u >> 16) & 1u);   // round-to-nearest-even
    return (ushort_t)(u >> 16);
}

// ---------------------------------------------------------------- K1: fused v-projection + xsum partials
// vf[b][mblk48][n][ks32][cg2][lane64][elem8]
__global__ __launch_bounds__(256, 4) void k_vproj(const float* __restrict__ x,
                                                  const float* __restrict__ Wv,
                                                  const float* __restrict__ bv,
                                                  ushort_t* __restrict__ vf,
                                                  float* __restrict__ xsp) {
    __shared__ __align__(16) ushort_t xbf[64 * 72];
    __shared__ __align__(16) ushort_t WvT[64 * 72];
    __shared__ __align__(16) ushort_t vst[64 * 72];

    int tid = threadIdx.x;
    int bid = blockIdx.x;            // 512 = 4b * 8tt * 16mg
    int mg = bid & 15;
    int tt = (bid >> 4) & 7;
    int b = bid >> 7;
    int t0 = tt * 64;
    int mbase = mg * 12;
    int cnt = (mbase + 12 <= MDIM) ? 12 : (MDIM - mbase);   // 12 or 10

    int w = tid >> 6, lane = tid & 63;
    int la = lane & 15, lb = lane >> 4;
    int r = tid >> 2, seg = tid & 3;

    int chunk = tid >> 3, u = tid & 7;
    int ksr = chunk >> 3;
    int nn2 = (chunk >> 1) & 3;
    int lhi2 = chunk & 1;
    int d0 = u * 2;

#pragma unroll
    for (int rep = 0; rep < 16; ++rep) {
        int j = rep * 256 + tid;
        int ci = j >> 6, co = j & 63;
        WvT[co * 72 + ci] = f2bf(Wv[j]);
    }
    float bvv[4];
#pragma unroll
    for (int cf = 0; cf < 4; ++cf) bvv[cf] = bv[16 * cf + la];

    float xacc[16];
#pragma unroll
    for (int u2 = 0; u2 < 16; ++u2) xacc[u2] = 0.f;

    const size_t mstride = (size_t)TDIM * CDIM;  // 32768
    size_t xaddr = ((size_t)(b * MDIM + mbase) * TDIM + t0 + r) * CDIM + seg * 16;

    float4 xv[4];
#pragma unroll
    for (int u2 = 0; u2 < 4; ++u2) xv[u2] = *(const float4*)(x + xaddr + u2 * 4);

    f32x4 zz = {0.f, 0.f, 0.f, 0.f};

    for (int i = 0; i < cnt; ++i) {
#pragma unroll
        for (int u2 = 0; u2 < 4; ++u2) {
            xacc[u2 * 4 + 0] += xv[u2].x;
            xacc[u2 * 4 + 1] += xv[u2].y;
            xacc[u2 * 4 + 2] += xv[u2].z;
            xacc[u2 * 4 + 3] += xv[u2].w;
            ushort4 h;
            h.x = f2bf(xv[u2].x); h.y = f2bf(xv[u2].y);
            h.z = f2bf(xv[u2].z); h.w = f2bf(xv[u2].w);
            *(ushort4*)&xbf[r * 72 + seg * 16 + u2 * 4] = h;
        }
        __syncthreads();

        int inext = (i + 1 < cnt) ? (i + 1) : i;
        size_t xaddr2 = xaddr + (size_t)(inext - i) * mstride;
        float4 xv2[4];
#pragma unroll
        for (int u2 = 0; u2 < 4; ++u2) xv2[u2] = *(const float4*)(x + xaddr2 + u2 * 4);

        f32x4 acc2[4];
#pragma unroll
        for (int cf = 0; cf < 4; ++cf) acc2[cf] = zz;
#pragma unroll
        for (int ks = 0; ks < 2; ++ks) {
            bf16x8 aa = *(const bf16x8*)&xbf[(w * 16 + la) * 72 + ks * 32 + lb * 8];
#pragma unroll
            for (int cf = 0; cf < 4; ++cf) {
                bf16x8 bb = *(const bf16x8*)&WvT[(16 * cf + la) * 72 + ks * 32 + lb * 8];
                acc2[cf] = __builtin_amdgcn_mfma_f32_16x16x32_bf16(aa, bb, acc2[cf], 0, 0, 0);
            }
        }
#pragma unroll
        for (int cf = 0; cf < 4; ++cf) {
            ushort4 h;
            h.x = f2bf(acc2[cf][0] + bvv[cf]);
            h.y = f2bf(acc2[cf][1] + bvv[cf]);
            h.z = f2bf(acc2[cf][2] + bvv[cf]);
            h.w = f2bf(acc2[cf][3] + bvv[cf]);
            *(ushort4*)&vst[(16 * cf + la) * 72 + w * 16 + lb * 4] = h;   // vst[c][t_rel]
        }
        __syncthreads();

        int m = mbase + i;
        int mblk = m >> 2, mrel = m & 3;
        int cg = mrel >> 1, half = mrel & 1;
        size_t vfbase = ((((size_t)(b * 48 + mblk) * 4 + nn2) * 32 + (tt * 4 + ksr)) * 2 + cg) * 512
                      + (size_t)(lhi2 * 32 + half * 16 + d0) * 8;
        uint4 v0 = *(const uint4*)&vst[(nn2 * 16 + d0) * 72 + ksr * 16 + lhi2 * 8];
        uint4 v1 = *(const uint4*)&vst[(nn2 * 16 + d0 + 1) * 72 + ksr * 16 + lhi2 * 8];
        *(uint4*)(vf + vfbase) = v0;
        *(uint4*)(vf + vfbase + 8) = v1;

#pragma unroll
        for (int u2 = 0; u2 < 4; ++u2) xv[u2] = xv2[u2];
        xaddr = xaddr2;
    }

    if (mg == 15) {
        uint4 z4 = {0u, 0u, 0u, 0u};
#pragma unroll
        for (int pm = 190; pm < 192; ++pm) {
            int mblk = pm >> 2, mrel = pm & 3;
            int cg = mrel >> 1, half = mrel & 1;
            size_t vfbase = ((((size_t)(b * 48 + mblk) * 4 + nn2) * 32 + (tt * 4 + ksr)) * 2 + cg) * 512
                          + (size_t)(lhi2 * 32 + half * 16 + d0) * 8;
            *(uint4*)(vf + vfbase) = z4;
            *(uint4*)(vf + vfbase + 8) = z4;
        }
    }

    size_t sbase = ((size_t)(mg * 4 + b) * TDIM + t0 + r) * CDIM + seg * 16;
#pragma unroll
    for (int u2 = 0; u2 < 4; ++u2) {
        float4 o;
        o.x = xacc[u2 * 4 + 0]; o.y = xacc[u2 * 4 + 1];
        o.z = xacc[u2 * 4 + 2]; o.w = xacc[u2 * 4 + 3];
        *(float4*)(xsp + sbase + u2 * 4) = o;
    }
}

// ---------------------------------------------------------------- K1b: reduce 16 partials -> xsum; block 0 builds wpf
__global__ __launch_bounds__(256) void k_xsum2(const float* __restrict__ xsp,
                                               const float* __restrict__ Wp,
                                               float* __restrict__ xsum,
                                               ushort_t* __restrict__ wpf) {
    int tid = threadIdx.x;
    int idx = blockIdx.x * 256 + tid;   // 131072
    float s = 0.f;
#pragma unroll
    for (int p = 0; p < 16; ++p) s += xsp[(size_t)p * 131072 + idx];
    xsum[idx] = s;

    if (blockIdx.x == 0) {
#pragma unroll
        for (int rp = 0; rp < 16; ++rp) {
            int u = rp * 256 + tid;            // 0..4095
            int cf = u >> 11, kk = (u >> 9) & 3, lf = (u >> 3) & 63, j = u & 7;
            wpf[u] = f2bf(Wp[(kk * 16 + (lf >> 5) * 8 + j) * 64 + cf * 32 + (lf & 31)]);
        }
    }
}

// ---------------------------------------------------------------- K2: weights (qt/kt + softmax), frag-order output
__global__ __launch_bounds__(256) void k_weights(const float* __restrict__ xsum,
                                                 const float* __restrict__ Wq,
                                                 const float* __restrict__ bq,
                                                 const float* __restrict__ Wk,
                                                 const float* __restrict__ bk,
                                                 ushort_t* __restrict__ wf,
                                                 float* __restrict__ a_out) {
    __shared__ __align__(16) float kt[512][20];
    __shared__ __align__(16) float qt[32][20];
    __shared__ __align__(16) float xs[64][68];
    __shared__ __align__(16) float wcol[64][16];
    __shared__ float kbias[16], qbias[16];
    __shared__ __align__(16) ushort_t rowbuf[32][520];

    int tid = threadIdx.x;
    int bid = blockIdx.x;        // 256 blocks
    int tcn = bid & 15;          // t-chunk (32 rows) == tq
    int n = (bid >> 4) & 3;
    int b = bid >> 6;
    int t0 = tcn * 32;

    for (int j = tid; j < 1024; j += 256) {
        int c = j >> 4, d = j & 15;
        wcol[c][d] = Wk[c * 64 + n * 16 + d];
    }
    if (tid < 16) kbias[tid] = 190.0f * bk[n * 16 + tid];
    if (tid >= 16 && tid < 32) qbias[tid - 16] = 190.0f * bq[n * 16 + tid - 16];
    __syncthreads();

    for (int ch = 0; ch < 8; ++ch) {
        for (int j = tid; j < 4096; j += 256) {
            int t = j >> 6, c = j & 63;
            xs[t][c] = xsum[((size_t)(b * 512) + (ch * 64 + t)) * 64 + c];
        }
        __syncthreads();
#pragma unroll
        for (int o = 0; o < 4; ++o) {
            int oi = o * 256 + tid;
            int t = oi >> 4, d = oi & 15;
            float s = 0.f;
#pragma unroll
            for (int c = 0; c < 64; ++c) s += xs[t][c] * wcol[c][d];
            kt[ch * 64 + t][d] = s + kbias[d];
        }
        __syncthreads();
    }

    for (int j = tid; j < 1024; j += 256) {
        int c = j >> 4, d = j & 15;
        wcol[c][d] = Wq[c * 64 + n * 16 + d];
    }
    for (int j = tid; j < 2048; j += 256) {
        int t = j >> 6, c = j & 63;
        xs[t][c] = xsum[((size_t)(b * 512) + (t0 + t)) * 64 + c];
    }
    __syncthreads();
#pragma unroll
    for (int o = 0; o < 2; ++o) {
        int oi = o * 256 + tid;
        int t = oi >> 4, d = oi & 15;
        float s = 0.f;
#pragma unroll
        for (int c = 0; c < 64; ++c) s += xs[t][c] * wcol[c][d];
        qt[t][d] = s + qbias[d];
    }
    __syncthreads();

    const float scale = 0.01813692f;  // 1/sqrt(16*190)
    int w = tid >> 6, lane = tid & 63;
    for (int rr = 0; rr < 8; ++rr) {
        int r = w * 8 + rr;
        float qreg[16];
#pragma unroll
        for (int d = 0; d < 16; ++d) qreg[d] = qt[r][d];
        float lv[8];
#pragma unroll
        for (int i = 0; i < 8; ++i) {
            int k = lane + 64 * i;
            const float* kr = &kt[k][0];
            float s = 0.f;
#pragma unroll
            for (int d = 0; d < 16; ++d) s += qreg[d] * kr[d];
            lv[i] = s * scale;
        }
        float mx = lv[0];
#pragma unroll
        for (int i = 1; i < 8; ++i) mx = fmaxf(mx, lv[i]);
#pragma unroll
        for (int off = 32; off >= 1; off >>= 1) mx = fmaxf(mx, __shfl_xor(mx, off));
        float se = 0.f;
#pragma unroll
        for (int i = 0; i < 8; ++i) { lv[i] = __expf(lv[i] - mx); se += lv[i]; }
#pragma unroll
        for (int off = 32; off >= 1; off >>= 1) se += __shfl_xor(se, off);
        float inv = 1.0f / se;

        size_t abase = ((size_t)(n * 512 + (t0 + r))) * 512;
#pragma unroll
        for (int i = 0; i < 8; ++i) {
            float wv = lv[i] * inv;
            rowbuf[r][lane + 64 * i] = f2bf(wv);
            if (b == 0) a_out[abase + lane + 64 * i] = wv;
        }
    }
    __syncthreads();

    size_t wfbase = ((size_t)((b * 4 + n) * 16 + tcn)) * 32 * 512;
#pragma unroll
    for (int p = 0; p < 8; ++p) {
        int id = p * 256 + tid;          // 0..2047
        int ks = id >> 6;
        int lf = id & 63;
        int l31 = lf & 31, lhi = lf >> 5;
        uint4 v = *(const uint4*)&rowbuf[l31][ks * 16 + lhi * 8];
        *(uint4*)(wf + wfbase + (size_t)ks * 512 + lf * 8) = v;
    }
}

// ---------------------------------------------------------------- K4: register-direct att GEMM, block=(b,8m,128t),
// 8 waves=(n, m-half), acc 128, E/O counted-vmcnt(6) pipeline.
// Grid order: tt FASTEST (R7's proven-L2-friendly order; R12's mq-fastest thrashed W to HBM).
__global__ __launch_bounds__(512, 2) void k_att(const ushort_t* __restrict__ wf,
                                                const ushort_t* __restrict__ vf,
                                                const ushort_t* __restrict__ wpf,
                                                const float* __restrict__ bp,
                                                float* __restrict__ out) {
    __shared__ __align__(16) ushort_t attS[32768];   // 64 KB, XOR-swizzled rows

    int tid = threadIdx.x;
    int bid0 = blockIdx.x;                     // 384 = 4b * 24mq * 4tt
    int bid = (bid0 & 7) * 48 + (bid0 >> 3);   // XCD x -> logical [48x, 48x+48): same b, 12 mq, all tt
    int tt = bid & 3;                          // 128-t tile (fastest: consecutive blocks share V slice)
    int mq = (bid >> 2) % 24;                  // 8 m each
    int b = bid / 96;

    int wid = tid >> 6, lane = tid & 63;
    int l31 = lane & 31, lhi = lane >> 5;
    int n = wid >> 1;        // head
    int mh = wid & 1;        // m-half: mblk = mq*2 + mh
    int mblk = mq * 2 + mh;

    // A: q = t-32-group within the 128t tile
    unsigned abase[4];
#pragma unroll
    for (int q = 0; q < 4; ++q)
        abase[q] = (unsigned)((((b * 4 + n) * 16 + tt * 4 + q) * 32) * 512 + lane * 8);
    // B: cg = col-32-group (2m x 16d each)
    unsigned bbase[2];
#pragma unroll
    for (int j = 0; j < 2; ++j)
        bbase[j] = (unsigned)(((((b * 48 + mblk) * 4 + n) * 32) * 2 + j) * 512 + lane * 8);

    f32x16 acc[4][2];
#pragma unroll
    for (int q = 0; q < 4; ++q)
#pragma unroll
        for (int j = 0; j < 2; ++j) acc[q][j] = (f32x16)(0.f);

    bf16x8 Ae[4], Be[2], Ao[4], Bo[2];

#define LOADC(A_, B_, KS) do {                                                    \
    _Pragma("unroll")                                                             \
    for (int q = 0; q < 4; ++q)                                                   \
        A_[q] = *(const bf16x8*)(wf + abase[q] + (KS) * 512);                     \
    _Pragma("unroll")                                                             \
    for (int j = 0; j < 2; ++j)                                                   \
        B_[j] = *(const bf16x8*)(vf + bbase[j] + (KS) * 1024);                    \
} while (0)

#define COMPC(A_, B_) do {                                                        \
    _Pragma("unroll")                                                             \
    for (int j = 0; j < 2; ++j)                                                   \
        _Pragma("unroll")                                                         \
        for (int q = 0; q < 4; ++q)                                               \
            acc[q][j] = __builtin_amdgcn_mfma_f32_32x32x16_bf16(A_[q], B_[j], acc[q][j], 0, 0, 0); \
} while (0)

#define VMW(N) do { asm volatile("s_waitcnt vmcnt(" #N ")" ::: "memory"); __builtin_amdgcn_sched_barrier(0); } while (0)

    LOADC(Ae, Be, 0);
    LOADC(Ao, Bo, 1);
#pragma unroll
    for (int kc = 0; kc < 30; kc += 2) {
        VMW(6);  COMPC(Ae, Be);  LOADC(Ae, Be, kc + 2);
        VMW(6);  COMPC(Ao, Bo);  LOADC(Ao, Bo, kc + 3);
    }
    VMW(6);  COMPC(Ae, Be);      // ks 30
    VMW(0);  COMPC(Ao, Bo);      // ks 31
#undef LOADC
#undef COMPC
#undef VMW

    // ---- epilogue: two 4m passes; attS[4m][128t][64c] XOR-swizzled; GEMM2 via wpf frags
    float bpv[2];
#pragma unroll
    for (int cf = 0; cf < 2; ++cf) bpv[cf] = bp[cf * 32 + l31];

    int mloc2 = wid >> 1;      // GEMM2: m row within the 4m pass
    int th2 = wid & 1;         // 64-t half

#pragma unroll
    for (int h = 0; h < 2; ++h) {
        __syncthreads();
        if (mh == h) {
            int mloc = ((l31 >> 4));           // + cg*2
            int d = l31 & 15;
#pragma unroll
            for (int cg = 0; cg < 2; ++cg)
#pragma unroll
                for (int q = 0; q < 4; ++q) {
                    f32x16 a = acc[q][cg];
                    int ml = cg * 2 + mloc;
#pragma unroll
                    for (int r = 0; r < 16; ++r) {
                        int tl = q * 32 + (r & 3) + 8 * (r >> 2) + 4 * lhi;
                        int idx = (((ml * 128 + tl) * 64) + n * 16 + d) ^ ((tl & 7) << 3);
                        attS[idx] = f2bf(a[r]);
                    }
                }
        }
        __syncthreads();

        f32x16 acc2[2][2];
#pragma unroll
        for (int q2 = 0; q2 < 2; ++q2)
#pragma unroll
            for (int cf = 0; cf < 2; ++cf) acc2[q2][cf] = (f32x16)(0.f);
#pragma unroll
        for (int kk = 0; kk < 4; ++kk) {
            bf16x8 bbf[2];
#pragma unroll
            for (int cf = 0; cf < 2; ++cf)
                bbf[cf] = *(const bf16x8*)(wpf + (cf * 4 + kk) * 512 + lane * 8);
#pragma unroll
            for (int q2 = 0; q2 < 2; ++q2) {
                int tl = th2 * 64 + q2 * 32 + l31;
                int aidx = (((mloc2 * 128 + tl) * 64) + kk * 16 + lhi * 8) ^ ((tl & 7) << 3);
                bf16x8 aa = *(const bf16x8*)(attS + aidx);
#pragma unroll
                for (int cf = 0; cf < 2; ++cf)
                    acc2[q2][cf] = __builtin_amdgcn_mfma_f32_32x32x16_bf16(aa, bbf[cf], acc2[q2][cf], 0, 0, 0);
            }
        }
        int m = mq * 8 + h * 4 + mloc2;
        if (m < 190) {
            size_t obase = ((size_t)(b * 190 + m) * 512 + tt * 128 + th2 * 64) * 64;
#pragma unroll
            for (int q2 = 0; q2 < 2; ++q2)
#pragma unroll
                for (int cf = 0; cf < 2; ++cf)
#pragma unroll
                    for (int r = 0; r < 16; ++r) {
                        int ts = q2 * 32 + (r & 3) + 8 * (r >> 2) + 4 * lhi;
                        out[obase + (size_t)ts * 64 + cf * 32 + l31] = acc2[q2][cf][r] + bpv[cf];
                    }
        }
    }
}

// ----------------------------------------------------------------
extern "C" void kernel_launch(void* const* d_in, const int* in_sizes, int n_in,
                              void* d_out, int out_size, void* d_ws, size_t ws_size,
                              hipStream_t stream) {
    const float* x  = (const float*)d_in[0];
    const float* Wq = (const float*)d_in[1];
    const float* bq = (const float*)d_in[2];
    const float* Wk = (const float*)d_in[3];
    const float* bk = (const float*)d_in[4];
    const float* Wv = (const float*)d_in[5];
    const float* bv = (const float*)d_in[6];
    const float* Wp = (const float*)d_in[7];
    const float* bp = (const float*)d_in[8];

    float* out = (float*)d_out;
    float* a_out = out + (size_t)BSZ * MDIM * TDIM * CDIM;   // 24903680

    // xsum partials in the out region (8 MB), fully overwritten by k_att later.
    float* xsp = out;

    float* xsum = (float*)d_ws;                                         // 512 KB
    ushort_t* wf = (ushort_t*)((char*)d_ws + 524288);                   // 8.39 MB
    ushort_t* vf = (ushort_t*)((char*)d_ws + 524288 + 8388608);         // 50.33 MB
    ushort_t* wpf = (ushort_t*)((char*)d_ws + 524288 + 8388608 + 50331648);  // 8 KB

    k_vproj<<<512, 256, 0, stream>>>(x, Wv, bv, vf, xsp);
    k_xsum2<<<512, 256, 0, stream>>>(xsp, Wp, xsum, wpf);
    k_weights<<<256, 256, 0, stream>>>(xsum, Wq, bq, Wk, bk, wf, a_out);
    k_att<<<384, 512, 0, stream>>>(wf, vf, wpf, bp, out);
}